// Round 4
// baseline (1990.835 us; speedup 1.0000x reference)
//
#include <hip/hip_runtime.h>
#include <stdint.h>

#define BATCH 2048
#define TSEQ  64
#define DIN   512
#define HID   1024
#define CIN   1536   // DIN + HID

#define BM 128
#define BN 32
#define BK 64
#define KITERS (CIN / BK)   // 24

// LDS geometry: 8-row chunks of 128 B rows (1024 B data) + 64 B pad -> stride 1088 B.
// (r>>3) chunk step lands +16 banks; row-within-chunk +0; lane quads +4; 8/8 lane split
// covers +0/+16 -> b128 fragment reads hit all 32 banks exactly 8x (optimal throughput).
#define CHUNK   1088
#define A_CHUNKS 16                     // 128 rows
#define B_CHUNKS 4                      // 32 rows per matrix
#define A_BYTES (A_CHUNKS * CHUNK)      // 17408
#define B_MAT   (B_CHUNKS * CHUNK)      // 4352
#define B_BYTES (3 * B_MAT)             // 13056
// A triple-buffered (2-phase prefetch lead) + B double-buffered (1-phase lead):
// 3*17408 + 2*13056 = 78336 B/block; x2 blocks = 156672 <= 163840 -> still 2 blocks/CU.

typedef __attribute__((ext_vector_type(8))) short bf16x8;
typedef __attribute__((ext_vector_type(4))) float f32x4;
typedef __attribute__((ext_vector_type(4))) float fvec4;
typedef __attribute__((ext_vector_type(4))) unsigned int uvec4;

// RNE float -> bf16 (bits)
__device__ __forceinline__ unsigned short f2bf(float f) {
    unsigned int u = __float_as_uint(f);
    u += 0x7fffu + ((u >> 16) & 1u);
    return (unsigned short)(u >> 16);
}
__device__ __forceinline__ float bf2f(unsigned short u) {
    return __uint_as_float(((unsigned int)u) << 16);
}

// async global->LDS, 16B per lane; lane i lands at ldsbase + i*16 (wave-uniform base).
__device__ __forceinline__ void gload_lds16(const void* g, void* lds) {
    __builtin_amdgcn_global_load_lds(
        (const __attribute__((address_space(1))) void*)(uintptr_t)g,
        (__attribute__((address_space(3))) void*)(unsigned)(uintptr_t)lds,
        16, 0, 0);
}

// ---------------- weight conversion: fp32 -> bf16, 3 matrices [HID][CIN] ----------------
__global__ __launch_bounds__(256) void convert_w(const float* __restrict__ Wf,
                                                 const float* __restrict__ Wg,
                                                 const float* __restrict__ Wh,
                                                 unsigned short* __restrict__ Wb) {
    int mat = blockIdx.y;
    const float* src = (mat == 0) ? Wf : ((mat == 1) ? Wg : Wh);
    size_t base = (size_t)mat * (size_t)(HID * CIN);
    size_t idx = ((size_t)blockIdx.x * 256 + threadIdx.x) * 8;
    const fvec4* s = (const fvec4*)(src + idx);
    fvec4 a = s[0], b = s[1];
    uvec4 o;
    o.x = (unsigned)f2bf(a.x) | ((unsigned)f2bf(a.y) << 16);
    o.y = (unsigned)f2bf(a.z) | ((unsigned)f2bf(a.w) << 16);
    o.z = (unsigned)f2bf(b.x) | ((unsigned)f2bf(b.y) << 16);
    o.w = (unsigned)f2bf(b.z) | ((unsigned)f2bf(b.w) << 16);
    *(uvec4*)(Wb + base + idx) = o;
}

// ---------------- x conversion: [B][T][D] fp32 -> [T][B][D] bf16 (time-major) ----------------
__global__ __launch_bounds__(256) void convert_x(const float* __restrict__ x,
                                                 unsigned short* __restrict__ xb) {
    size_t e = ((size_t)blockIdx.x * 256 + threadIdx.x) * 8;
    int t   = (int)(e / ((size_t)BATCH * DIN));
    int rem = (int)(e % ((size_t)BATCH * DIN));
    int b = rem / DIN;
    int d = rem % DIN;
    const float* src = x + ((size_t)b * TSEQ + t) * DIN + d;
    fvec4 a = *(const fvec4*)src;
    fvec4 c = *(const fvec4*)(src + 4);
    uvec4 o;
    o.x = (unsigned)f2bf(a.x) | ((unsigned)f2bf(a.y) << 16);
    o.y = (unsigned)f2bf(a.z) | ((unsigned)f2bf(a.w) << 16);
    o.z = (unsigned)f2bf(c.x) | ((unsigned)f2bf(c.y) << 16);
    o.w = (unsigned)f2bf(c.z) | ((unsigned)f2bf(c.w) << 16);
    *(uvec4*)(xb + e) = o;
}

// ---------------- one recurrence step: fused 3xGEMM + gate ----------------
// R3: counted-vmcnt pipeline (T4): per-wave issue ...B(p), A(p+1), B(p+1), A(p+2)...
// (7 loads/wave/phase uniform); top of phase p: lgkmcnt(0) + vmcnt(4) + s_barrier
// retires exactly {A(p),B(p)} while A(p+1..2)/B(p+1) stay in flight across the barrier.
// R4: k-split wave decomposition (wm, kh): wave = 64-row half x 32-k half, all 32 cols.
// A-fragment reads have zero wave-amplification (was 2x): ds_read instr/CU/phase 112->80.
// One LDS cross-wave kh-reduction per STEP (reuses ldsA as 48 KB exchange buffer).
__global__ __launch_bounds__(256, 2) void step_kernel(
    const unsigned short* __restrict__ xb,     // bf16 [TSEQ][BATCH][DIN]
    const unsigned short* __restrict__ Wb,     // bf16 [3][HID][CIN]
    const float* __restrict__ bfv,
    const float* __restrict__ bgv,
    const float* __restrict__ bhv,
    const unsigned short* __restrict__ hin,    // bf16 [BATCH][HID]
    unsigned short* __restrict__ hout,         // bf16 [BATCH][HID]
    int t)
{
    __shared__ __align__(16) char ldsA[3][A_BYTES];   // 52224 B (also: 48 KB kh-exchange)
    __shared__ __align__(16) char ldsB[2][B_BYTES];   // 26112 B

    const int tid  = threadIdx.x;
    const int bid  = blockIdx.x;
    // n-affinity XCD swizzle: XCD (bid&7) sees n_tiles {4k..4k+3} -> 1.18 MB weight slice in L2
    const int n_tile = ((bid & 7) << 2) | ((bid >> 3) & 3);   // 0..31
    const int m_tile = bid >> 5;                              // 0..15
    const int m0 = m_tile * BM;
    const int n0 = n_tile * BN;

    const int lane = tid & 63;
    const int wave = tid >> 6;       // 0..3
    const int wm = wave >> 1;        // 0..1 : 64-row half
    const int kh = wave & 1;         // 0..1 : 32-k half of each 64-k phase

    // DMA lane mapping inside an 8-row x 128 B chunk
    const int drow = lane >> 3;          // 0..7
    const int dcol = (lane & 7) * 8;     // elem col 0..56

    f32x4 acc[3][4][2] = {};             // [mat][mt][nt] — 96 VGPRs

    float biasF[2], biasG[2], biasH[2];
#pragma unroll
    for (int nt = 0; nt < 2; ++nt) {
        int cgn = n0 + nt * 16 + (lane & 15);
        biasF[nt] = bfv[cgn];
        biasG[nt] = bgv[cgn];
        biasH[nt] = bhv[cgn];
    }

    const unsigned short* xsrc = xb + (size_t)t * BATCH * DIN;

    // precomputed A-fragment read offsets (bytes)
    int aoff[4];
#pragma unroll
    for (int mt = 0; mt < 4; ++mt) {
        int r = wm * 64 + mt * 16 + (lane & 15);
        aoff[mt] = (r >> 3) * CHUNK + (r & 7) * 128;
    }
    int boff[2];
#pragma unroll
    for (int nt = 0; nt < 2; ++nt) {
        int nloc = nt * 16 + (lane & 15);
        boff[nt] = (nloc >> 3) * CHUNK + (nloc & 7) * 128;
    }
    // this wave's k-slice within a 128-B (64-elem) row: kh half + lane-quad subslice
    const int kb = kh * 64 + (lane >> 4) * 16;

    auto stageA = [&](int ki, char* base) {
        const int k0 = ki * BK;
        const unsigned short* asrc;
        int astride;
        if (k0 < DIN) { asrc = xsrc + k0;        astride = DIN; }
        else          { asrc = hin + (k0 - DIN); astride = HID; }
        // wave w stages chunks 4w..4w+3 (rows 32w..32w+31): 4 loads/wave
#pragma unroll
        for (int c = 0; c < 4; ++c) {
            int chunk = wave * 4 + c;
            gload_lds16(asrc + (size_t)(m0 + chunk * 8 + drow) * astride + dcol,
                        base + chunk * CHUNK);
        }
    };
    auto stageB = [&](int ki, char* base) {
        const int k0 = ki * BK;
        // 12 chunk-units (mat = u>>2, chunk = u&3); wave w stages u = 3w..3w+2: 3 loads/wave
#pragma unroll
        for (int j = 0; j < 3; ++j) {
            int u = wave * 3 + j;
            int mat = u >> 2, chunk = u & 3;
            gload_lds16(Wb + (size_t)mat * (HID * CIN) + (size_t)(n0 + chunk * 8 + drow) * CIN
                           + k0 + dcol,
                        base + mat * B_MAT + chunk * CHUNK);
        }
    };
    auto compute = [&](const char* baseA, const char* baseB) {
        bf16x8 af[4];
#pragma unroll
        for (int mt = 0; mt < 4; ++mt)
            af[mt] = *(const bf16x8*)(baseA + aoff[mt] + kb);
#pragma unroll
        for (int mat = 0; mat < 3; ++mat)
#pragma unroll
            for (int nt = 0; nt < 2; ++nt) {
                bf16x8 bq = *(const bf16x8*)(baseB + mat * B_MAT + boff[nt] + kb);
#pragma unroll
                for (int mt = 0; mt < 4; ++mt)
                    acc[mat][mt][nt] = __builtin_amdgcn_mfma_f32_16x16x32_bf16(
                        af[mt], bq, acc[mat][mt][nt], 0, 0, 0);
            }
    };

    // prologue issue order (must match steady-state vmcnt accounting): A(0), B(0), A(1)
    stageA(0, ldsA[0]);
    stageB(0, ldsB[0]);
    stageA(1, ldsA[1]);

#pragma unroll
    for (int p = 0; p < KITERS - 1; ++p) {            // phases 0..22
        // single asm block: waits + barrier, fully ordered vs all memory ops
        asm volatile("s_waitcnt vmcnt(4) lgkmcnt(0)\n\ts_barrier" ::: "memory");
        stageB(p + 1, ldsB[(p + 1) & 1]);             // 1-phase lead (L2-resident weights)
        if (p + 2 < KITERS) stageA(p + 2, ldsA[(p + 2) % 3]);  // 2-phase lead (x/h via L3/HBM)
        compute(ldsA[p % 3], ldsB[p & 1]);
    }
    // peeled last phase (p = 23): nothing left in flight to keep -> full drain
    asm volatile("s_waitcnt vmcnt(0) lgkmcnt(0)\n\ts_barrier" ::: "memory");
    compute(ldsA[(KITERS - 1) % 3], ldsB[(KITERS - 1) & 1]);

    // ---- kh cross-wave reduction (once per step) ----
    __syncthreads();                       // all LDS reads done -> ldsA reusable as exchange
    float* xch = (float*)&ldsA[0][0];      // 2 x 24 KB, contiguous [wm][idx][lane] f32x4
    if (kh == 1) {
        f32x4* dst = (f32x4*)xch + (size_t)wm * (24 * 64) + lane;
#pragma unroll
        for (int mat = 0; mat < 3; ++mat)
#pragma unroll
            for (int mt = 0; mt < 4; ++mt)
#pragma unroll
                for (int nt = 0; nt < 2; ++nt)
                    dst[((mat * 4 + mt) * 2 + nt) * 64] = acc[mat][mt][nt];
    }
    __syncthreads();
    if (kh == 0) {
        const f32x4* src = (const f32x4*)xch + (size_t)wm * (24 * 64) + lane;
#pragma unroll
        for (int mat = 0; mat < 3; ++mat)
#pragma unroll
            for (int mt = 0; mt < 4; ++mt)
#pragma unroll
                for (int nt = 0; nt < 2; ++nt)
                    acc[mat][mt][nt] += src[((mat * 4 + mt) * 2 + nt) * 64];

        // epilogue: gate + NT store bf16 h_out (kh==0 waves only)
        // C/D layout (16x16x32): col = lane&15, row = (lane>>4)*4 + reg   [m89-verified]
#pragma unroll
        for (int mt = 0; mt < 4; ++mt) {
            int rbase = m0 + wm * 64 + mt * 16 + (lane >> 4) * 4;
#pragma unroll
            for (int nt = 0; nt < 2; ++nt) {
                int cgn = n0 + nt * 16 + (lane & 15);
#pragma unroll
                for (int r = 0; r < 4; ++r) {
                    float f  = acc[0][mt][nt][r] + biasF[nt];
                    float g  = acc[1][mt][nt][r] + biasG[nt];
                    float hh = acc[2][mt][nt][r] + biasH[nt];
                    float gate = 1.0f / (1.0f + __expf(f));   // sigmoid(-f)
                    float nh = hh + gate * (g - hh);
                    __builtin_nontemporal_store(f2bf(nh),
                        hout + (size_t)(rbase + r) * HID + cgn);
                }
            }
        }
    }
}

// ---------------- final FC: out[2048][2] = h @ Wfc^T + bfc ----------------
__global__ __launch_bounds__(256) void fc_kernel(const unsigned short* __restrict__ h,
                                                 const float* __restrict__ Wfc,
                                                 const float* __restrict__ bfc,
                                                 float* __restrict__ out) {
    int row = blockIdx.x;
    int tid = threadIdx.x;
    const unsigned short* hr = h + (size_t)row * HID;
    ushort4 hv = *(const ushort4*)(hr + tid * 4);
    float h0 = bf2f(hv.x), h1 = bf2f(hv.y), h2 = bf2f(hv.z), h3 = bf2f(hv.w);
    float4 w0 = *(const float4*)(Wfc + tid * 4);
    float4 w1 = *(const float4*)(Wfc + HID + tid * 4);
    float a0 = h0 * w0.x + h1 * w0.y + h2 * w0.z + h3 * w0.w;
    float a1 = h0 * w1.x + h1 * w1.y + h2 * w1.z + h3 * w1.w;
#pragma unroll
    for (int off = 32; off > 0; off >>= 1) {
        a0 += __shfl_down(a0, off);
        a1 += __shfl_down(a1, off);
    }
    __shared__ float red[2][4];
    if ((tid & 63) == 0) { red[0][tid >> 6] = a0; red[1][tid >> 6] = a1; }
    __syncthreads();
    if (tid == 0) out[(size_t)row * 2 + 0] = red[0][0] + red[0][1] + red[0][2] + red[0][3] + bfc[0];
    if (tid == 1) out[(size_t)row * 2 + 1] = red[1][0] + red[1][1] + red[1][2] + red[1][3] + bfc[1];
}

extern "C" void kernel_launch(void* const* d_in, const int* in_sizes, int n_in,
                              void* d_out, int out_size, void* d_ws, size_t ws_size,
                              hipStream_t stream) {
    const float* x   = (const float*)d_in[0];
    const float* Wf  = (const float*)d_in[1];
    const float* bfv = (const float*)d_in[2];
    const float* Wg  = (const float*)d_in[3];
    const float* bgv = (const float*)d_in[4];
    const float* Wh  = (const float*)d_in[5];
    const float* bhv = (const float*)d_in[6];
    const float* Wfc = (const float*)d_in[7];
    const float* bfc = (const float*)d_in[8];
    float* out = (float*)d_out;

    char* ws = (char*)d_ws;
    unsigned short* Wb = (unsigned short*)ws;                       // 9.4 MB
    size_t wb_bytes = (size_t)3 * HID * CIN * 2;
    size_t h_bytes  = (size_t)BATCH * HID * 2;                      // 4 MB
    unsigned short* h0 = (unsigned short*)(ws + wb_bytes);
    unsigned short* h1 = (unsigned short*)(ws + wb_bytes + h_bytes);
    unsigned short* xbuf = (unsigned short*)(ws + wb_bytes + 2 * h_bytes);  // 128 MB
    // total ws use ~146 MB (harness ws ~1 GiB)

    convert_w<<<dim3(768, 3), 256, 0, stream>>>(Wf, Wg, Wh, Wb);
    convert_x<<<32768, 256, 0, stream>>>(x, xbuf);
    (void)hipMemsetAsync(h0, 0, h_bytes, stream);                   // h_0 = 0 (capturable)

    unsigned short* bufs[2] = {h0, h1};
    for (int t = 0; t < TSEQ; ++t) {
        step_kernel<<<512, 256, 0, stream>>>(xbuf, Wb, bfv, bgv, bhv,
                                             bufs[t & 1], bufs[(t + 1) & 1], t);
    }
    // after 64 steps, final h is in bufs[0]
    fc_kernel<<<BATCH, 256, 0, stream>>>(h0, Wfc, bfc, out);
}